// Round 1
// baseline (392.019 us; speedup 1.0000x reference)
//
#include <hip/hip_runtime.h>
#include <hip/hip_bf16.h>

// Problem constants (from reference)
#define DIMX   768
#define HEADS  12
#define DH     64
#define INNER  768
#define NQKV   2304
#define SEQ    4096
#define BATCH  2
#define ROWS   (BATCH*SEQ)   // 8192
#define EPSF   1e-8f

typedef __bf16 bf16x8 __attribute__((ext_vector_type(8)));
typedef float  f32x4  __attribute__((ext_vector_type(4)));

// RNE f32 -> bf16 (finite inputs only)
__device__ __forceinline__ unsigned short f2bf(float f) {
    unsigned int u = __float_as_uint(f);
    unsigned int r = ((u >> 16) & 1u) + 0x7FFFu;
    return (unsigned short)((u + r) >> 16);
}

__global__ __launch_bounds__(256) void cast_f32_bf16(
    const float* __restrict__ src, unsigned short* __restrict__ dst, int n)
{
    int i = (blockIdx.x * 256 + threadIdx.x) * 4;
    if (i + 3 < n) {
        float4 v = *reinterpret_cast<const float4*>(src + i);
        ushort4 o;
        o.x = f2bf(v.x); o.y = f2bf(v.y); o.z = f2bf(v.z); o.w = f2bf(v.w);
        *reinterpret_cast<ushort4*>(dst + i) = o;
    }
}

// C[M][N] (f32) = A[M][K] (bf16) * B[N][K]^T (bf16)  (+ bias[col] if bias)
// 128x128 tile, BK=64, 4 waves in 2x2, each wave 64x64 via 4x4 16x16x32 frags.
__global__ __launch_bounds__(256) void gemm_bt_kernel(
    const unsigned short* __restrict__ A,
    const unsigned short* __restrict__ B,
    float* __restrict__ C,
    const float* __restrict__ bias,
    int M, int N, int K)
{
    __shared__ unsigned short shA[128][72];   // pad 64->72 elems (144B stride: 2-way banks, free)
    __shared__ unsigned short shB[128][72];

    const int bm0 = blockIdx.x * 128;
    const int bn0 = blockIdx.y * 128;
    const int tid = threadIdx.x;
    const int lane = tid & 63;
    const int wid  = tid >> 6;
    const int l15  = lane & 15;
    const int l4   = lane >> 4;
    const int wr   = wid >> 1;   // wave row (0..1) -> 64 rows
    const int wc   = wid & 1;    // wave col (0..1) -> 64 cols

    f32x4 acc[4][4];
    #pragma unroll
    for (int i = 0; i < 4; ++i)
        #pragma unroll
        for (int j = 0; j < 4; ++j)
            acc[i][j] = (f32x4){0.f, 0.f, 0.f, 0.f};

    const int nkt = K >> 6;
    for (int kt = 0; kt < nkt; ++kt) {
        const int k0 = kt << 6;
        __syncthreads();
        #pragma unroll
        for (int it = 0; it < 4; ++it) {
            int c = tid + it * 256;          // 1024 chunks of 8 bf16 per operand
            int row = c >> 3, colc = c & 7;
            *reinterpret_cast<uint4*>(&shA[row][colc * 8]) =
                *reinterpret_cast<const uint4*>(&A[(size_t)(bm0 + row) * K + k0 + colc * 8]);
            *reinterpret_cast<uint4*>(&shB[row][colc * 8]) =
                *reinterpret_cast<const uint4*>(&B[(size_t)(bn0 + row) * K + k0 + colc * 8]);
        }
        __syncthreads();
        #pragma unroll
        for (int ks = 0; ks < 2; ++ks) {
            bf16x8 af[4], bfr[4];
            #pragma unroll
            for (int mf = 0; mf < 4; ++mf)
                af[mf] = *reinterpret_cast<const bf16x8*>(&shA[wr * 64 + mf * 16 + l15][ks * 32 + l4 * 8]);
            #pragma unroll
            for (int nf = 0; nf < 4; ++nf)
                bfr[nf] = *reinterpret_cast<const bf16x8*>(&shB[wc * 64 + nf * 16 + l15][ks * 32 + l4 * 8]);
            #pragma unroll
            for (int mf = 0; mf < 4; ++mf)
                #pragma unroll
                for (int nf = 0; nf < 4; ++nf)
                    acc[mf][nf] = __builtin_amdgcn_mfma_f32_16x16x32_bf16(
                        af[mf], bfr[nf], acc[mf][nf], 0, 0, 0);
        }
    }

    // Epilogue: D row = (lane>>4)*4 + r, col = lane&15  [measured layout, guide §3]
    #pragma unroll
    for (int mf = 0; mf < 4; ++mf) {
        #pragma unroll
        for (int nf = 0; nf < 4; ++nf) {
            int col = bn0 + wc * 64 + nf * 16 + l15;
            float badd = bias ? bias[col] : 0.f;
            #pragma unroll
            for (int r = 0; r < 4; ++r) {
                int row = bm0 + wr * 64 + mf * 16 + l4 * 4 + r;
                C[(size_t)row * N + col] = acc[mf][nf][r] + badd;
            }
        }
    }
}

// Read qkv f32 [8192][2304]; cross-head L2 norm over h for q,k at fixed (b,n,d);
// write q,k normalized bf16 in (b,h,n,d); v bf16 transposed (b,h,d,n).
__global__ __launch_bounds__(256) void normalize_kernel(
    const float* __restrict__ qkv,
    unsigned short* __restrict__ qo,
    unsigned short* __restrict__ ko,
    unsigned short* __restrict__ vt)
{
    int t = blockIdx.x * 256 + threadIdx.x;   // 8192*64 threads
    int row = t >> 6;                         // b*4096+n
    int d = t & 63;
    int b = row >> 12;
    int n = row & 4095;
    const float* base = qkv + (size_t)row * NQKV;

    float qv[12], kv[12], vv[12];
    float sq = 0.f, sk = 0.f;
    #pragma unroll
    for (int h = 0; h < 12; ++h) {
        qv[h] = base[h * 64 + d];
        kv[h] = base[768 + h * 64 + d];
        vv[h] = base[1536 + h * 64 + d];
        sq += qv[h] * qv[h];
        sk += kv[h] * kv[h];
    }
    float rq = rsqrtf(sqrtf(sq) + EPSF);
    float rk = rsqrtf(sqrtf(sk) + EPSF);
    #pragma unroll
    for (int h = 0; h < 12; ++h) {
        size_t bh = (size_t)(b * 12 + h);
        qo[(bh * SEQ + n) * 64 + d] = f2bf(qv[h] * rq);
        ko[(bh * SEQ + n) * 64 + d] = f2bf(kv[h] * rk);
        vt[(bh * 64 + d) * SEQ + n] = f2bf(vv[h]);
    }
}

// Flash attention. Grid: (SEQ/128, BATCH*HEADS). 4 waves; wave owns 32 q-rows.
// Swapped QK^T: ST[kv][q] = mfma(Kfrag, Qfrag) -> softmax state lane-local (q = lane&15).
// P staged per-wave in LDS as [q][kv] (padded). O^T[d][q] = mfma(Vt, P^T): alpha/l lane-local.
__global__ __launch_bounds__(256) void attn_kernel(
    const unsigned short* __restrict__ qg,
    const unsigned short* __restrict__ kg,
    const unsigned short* __restrict__ vtg,
    const float* __restrict__ scale,
    unsigned short* __restrict__ attnout)
{
    __shared__ unsigned short shK[64][72];      // K tile [kv][d]
    __shared__ unsigned short shV[64][72];      // V^T tile [d][kv]
    __shared__ unsigned short shP[4][32][72];   // per-wave P [q][kv]

    const int qblk = blockIdx.x;
    const int bh   = blockIdx.y;
    const int b    = bh / HEADS;
    const int h    = bh % HEADS;
    const int tid  = threadIdx.x;
    const int lane = tid & 63;
    const int wid  = tid >> 6;
    const int l15  = lane & 15;
    const int l4   = lane >> 4;

    const float inv_scale = 1.0f / scale[h];

    // Q fragments in registers (reused all KV tiles): q = qblk*128 + wid*32 + wq*16 + l15
    bf16x8 qf[2][2];
    const unsigned short* qbase = qg + ((size_t)bh * SEQ + qblk * 128 + wid * 32) * 64;
    #pragma unroll
    for (int wq = 0; wq < 2; ++wq)
        #pragma unroll
        for (int ks = 0; ks < 2; ++ks)
            qf[wq][ks] = *reinterpret_cast<const bf16x8*>(
                &qbase[(size_t)(wq * 16 + l15) * 64 + ks * 32 + l4 * 8]);

    f32x4 ot[2][4];   // O^T frags: d = df*16 + l4*4 + r, q = wq*16 + l15
    #pragma unroll
    for (int wq = 0; wq < 2; ++wq)
        #pragma unroll
        for (int df = 0; df < 4; ++df)
            ot[wq][df] = (f32x4){0.f, 0.f, 0.f, 0.f};

    float m_st[2] = {-3.0e38f, -3.0e38f};
    float l_st[2] = {0.f, 0.f};

    const unsigned short* kbase = kg  + (size_t)bh * SEQ * 64;
    const unsigned short* vbase = vtg + (size_t)bh * 64 * SEQ;

    for (int kt = 0; kt < SEQ / 64; ++kt) {
        __syncthreads();
        #pragma unroll
        for (int it = 0; it < 2; ++it) {
            int c = tid + it * 256;
            int row = c >> 3, colc = c & 7;
            *reinterpret_cast<uint4*>(&shK[row][colc * 8]) =
                *reinterpret_cast<const uint4*>(&kbase[(size_t)(kt * 64 + row) * 64 + colc * 8]);
            *reinterpret_cast<uint4*>(&shV[row][colc * 8]) =
                *reinterpret_cast<const uint4*>(&vbase[(size_t)row * SEQ + kt * 64 + colc * 8]);
        }
        __syncthreads();

        // ---- S^T = K * Q^T ----
        f32x4 st[4][2];
        #pragma unroll
        for (int kvf = 0; kvf < 4; ++kvf)
            #pragma unroll
            for (int wq = 0; wq < 2; ++wq)
                st[kvf][wq] = (f32x4){0.f, 0.f, 0.f, 0.f};
        #pragma unroll
        for (int ks = 0; ks < 2; ++ks) {
            bf16x8 kf[4];
            #pragma unroll
            for (int kvf = 0; kvf < 4; ++kvf)
                kf[kvf] = *reinterpret_cast<const bf16x8*>(&shK[kvf * 16 + l15][ks * 32 + l4 * 8]);
            #pragma unroll
            for (int kvf = 0; kvf < 4; ++kvf)
                #pragma unroll
                for (int wq = 0; wq < 2; ++wq)
                    st[kvf][wq] = __builtin_amdgcn_mfma_f32_16x16x32_bf16(
                        kf[kvf], qf[wq][ks], st[kvf][wq], 0, 0, 0);
        }

        // ---- online softmax (per wq; state at q = wq*16 + l15) ----
        #pragma unroll
        for (int wq = 0; wq < 2; ++wq) {
            float v[16];
            float mx = -3.0e38f;
            #pragma unroll
            for (int kvf = 0; kvf < 4; ++kvf)
                #pragma unroll
                for (int r = 0; r < 4; ++r) {
                    float s = st[kvf][wq][r] * inv_scale;
                    v[kvf * 4 + r] = s;
                    mx = fmaxf(mx, s);
                }
            mx = fmaxf(mx, __shfl_xor(mx, 16));
            mx = fmaxf(mx, __shfl_xor(mx, 32));
            float m_new = fmaxf(m_st[wq], mx);
            float alpha = __expf(m_st[wq] - m_new);
            float sum = 0.f;
            unsigned short pb[16];
            #pragma unroll
            for (int i = 0; i < 16; ++i) {
                float p = __expf(v[i] - m_new);
                sum += p;
                pb[i] = f2bf(p);
            }
            sum += __shfl_xor(sum, 16);
            sum += __shfl_xor(sum, 32);
            l_st[wq] = l_st[wq] * alpha + sum;
            m_st[wq] = m_new;
            #pragma unroll
            for (int df = 0; df < 4; ++df)
                ot[wq][df] *= alpha;
            // write P[q][kv]: kv = kvf*16 + l4*4 + r (4 consecutive -> one b64)
            #pragma unroll
            for (int kvf = 0; kvf < 4; ++kvf) {
                unsigned long long pk =
                    (unsigned long long)pb[kvf * 4 + 0]        |
                    ((unsigned long long)pb[kvf * 4 + 1] << 16) |
                    ((unsigned long long)pb[kvf * 4 + 2] << 32) |
                    ((unsigned long long)pb[kvf * 4 + 3] << 48);
                *reinterpret_cast<unsigned long long*>(
                    &shP[wid][wq * 16 + l15][kvf * 16 + l4 * 4]) = pk;
            }
        }

        // ---- O^T += V^T * P^T ----
        #pragma unroll
        for (int ks = 0; ks < 2; ++ks) {
            bf16x8 vf[4];
            #pragma unroll
            for (int df = 0; df < 4; ++df)
                vf[df] = *reinterpret_cast<const bf16x8*>(&shV[df * 16 + l15][ks * 32 + l4 * 8]);
            bf16x8 pf[2];
            #pragma unroll
            for (int wq = 0; wq < 2; ++wq)
                pf[wq] = *reinterpret_cast<const bf16x8*>(&shP[wid][wq * 16 + l15][ks * 32 + l4 * 8]);
            #pragma unroll
            for (int df = 0; df < 4; ++df)
                #pragma unroll
                for (int wq = 0; wq < 2; ++wq)
                    ot[wq][df] = __builtin_amdgcn_mfma_f32_16x16x32_bf16(
                        vf[df], pf[wq], ot[wq][df], 0, 0, 0);
        }
    }

    // ---- epilogue: O = O^T / l, write bf16 to attn_out[(b,n)][h*64+d] ----
    #pragma unroll
    for (int wq = 0; wq < 2; ++wq) {
        float invl = 1.0f / l_st[wq];
        int nrow = qblk * 128 + wid * 32 + wq * 16 + l15;
        size_t rowbase = ((size_t)(b * SEQ + nrow)) * INNER + h * 64;
        #pragma unroll
        for (int df = 0; df < 4; ++df) {
            unsigned short o0 = f2bf(ot[wq][df][0] * invl);
            unsigned short o1 = f2bf(ot[wq][df][1] * invl);
            unsigned short o2 = f2bf(ot[wq][df][2] * invl);
            unsigned short o3 = f2bf(ot[wq][df][3] * invl);
            unsigned long long pk =
                (unsigned long long)o0 | ((unsigned long long)o1 << 16) |
                ((unsigned long long)o2 << 32) | ((unsigned long long)o3 << 48);
            *reinterpret_cast<unsigned long long*>(&attnout[rowbase + df * 16 + l4 * 4]) = pk;
        }
    }
}

extern "C" void kernel_launch(void* const* d_in, const int* in_sizes, int n_in,
                              void* d_out, int out_size, void* d_ws, size_t ws_size,
                              hipStream_t stream)
{
    const float* x      = (const float*)d_in[0];
    const float* w_qkv  = (const float*)d_in[1];
    const float* w_out  = (const float*)d_in[2];
    const float* b_out  = (const float*)d_in[3];
    const float* scale  = (const float*)d_in[4];
    float* out = (float*)d_out;
    char* ws = (char*)d_ws;

    // Workspace layout (bytes), all 256-aligned. Total ~136.5 MB.
    unsigned short* xb    = (unsigned short*)(ws);                 // 12,582,912
    unsigned short* wqkvb = (unsigned short*)(ws + 12582912);      //  3,538,944
    unsigned short* woutb = (unsigned short*)(ws + 16121856);      //  1,179,648
    unsigned short* attnb = (unsigned short*)(ws + 17301504);      // 12,582,912
    unsigned short* qb    = (unsigned short*)(ws + 29884416);      // 12,582,912
    unsigned short* kb    = (unsigned short*)(ws + 42467328);      // 12,582,912
    unsigned short* vtb   = (unsigned short*)(ws + 55050240);      // 12,582,912
    float*          qkvf  = (float*)(ws + 67633152);               // 75,497,472

    cast_f32_bf16<<<6144, 256, 0, stream>>>(x, xb, 6291456);
    cast_f32_bf16<<<1728, 256, 0, stream>>>(w_qkv, wqkvb, 1769472);
    cast_f32_bf16<<<576, 256, 0, stream>>>(w_out, woutb, 589824);

    gemm_bt_kernel<<<dim3(64, 18), 256, 0, stream>>>(xb, wqkvb, qkvf, nullptr, ROWS, NQKV, DIMX);

    normalize_kernel<<<2048, 256, 0, stream>>>(qkvf, qb, kb, vtb);

    attn_kernel<<<dim3(SEQ / 128, BATCH * HEADS), 256, 0, stream>>>(qb, kb, vtb, scale, attnb);

    gemm_bt_kernel<<<dim3(64, 6), 256, 0, stream>>>(attnb, woutb, out, b_out, ROWS, INNER, INNER);
}

// Round 3
// 328.026 us; speedup vs baseline: 1.1951x; 1.1951x over previous
//
#include <hip/hip_runtime.h>
#include <hip/hip_bf16.h>

// Problem constants (from reference)
#define DIMX   768
#define HEADS  12
#define DH     64
#define INNER  768
#define NQKV   2304
#define SEQ    4096
#define BATCH  2
#define ROWS   (BATCH*SEQ)   // 8192
#define EPSF   1e-8f
#define LOG2E  1.4426950408889634f

typedef __bf16 bf16x8 __attribute__((ext_vector_type(8)));
typedef float  f32x4  __attribute__((ext_vector_type(4)));
typedef float  f32x16 __attribute__((ext_vector_type(16)));

// RNE f32 -> bf16 (finite inputs only)
__device__ __forceinline__ unsigned short f2bf(float f) {
    unsigned int u = __float_as_uint(f);
    unsigned int r = ((u >> 16) & 1u) + 0x7FFFu;
    return (unsigned short)((u + r) >> 16);
}

// pack two f32 into a u32 of 2 bf16 (lo = a, hi = b) via native casts
__device__ __forceinline__ unsigned pkbf(float a, float b) {
    unsigned short la = __builtin_bit_cast(unsigned short, (__bf16)a);
    unsigned short lb = __builtin_bit_cast(unsigned short, (__bf16)b);
    return (unsigned)la | ((unsigned)lb << 16);
}

__global__ __launch_bounds__(256) void cast_f32_bf16(
    const float* __restrict__ src, unsigned short* __restrict__ dst, int n)
{
    int i = (blockIdx.x * 256 + threadIdx.x) * 4;
    if (i + 3 < n) {
        float4 v = *reinterpret_cast<const float4*>(src + i);
        ushort4 o;
        o.x = f2bf(v.x); o.y = f2bf(v.y); o.z = f2bf(v.z); o.w = f2bf(v.w);
        *reinterpret_cast<ushort4*>(dst + i) = o;
    }
}

// C[M][N] (f32) = A[M][K] (bf16) * B[N][K]^T (bf16)  (+ bias[col] if bias)
__global__ __launch_bounds__(256) void gemm_bt_kernel(
    const unsigned short* __restrict__ A,
    const unsigned short* __restrict__ B,
    float* __restrict__ C,
    const float* __restrict__ bias,
    int M, int N, int K)
{
    __shared__ unsigned short shA[128][72];
    __shared__ unsigned short shB[128][72];

    const int bm0 = blockIdx.x * 128;
    const int bn0 = blockIdx.y * 128;
    const int tid = threadIdx.x;
    const int lane = tid & 63;
    const int wid  = tid >> 6;
    const int l15  = lane & 15;
    const int l4   = lane >> 4;
    const int wr   = wid >> 1;
    const int wc   = wid & 1;

    f32x4 acc[4][4];
    #pragma unroll
    for (int i = 0; i < 4; ++i)
        #pragma unroll
        for (int j = 0; j < 4; ++j)
            acc[i][j] = (f32x4){0.f, 0.f, 0.f, 0.f};

    const int nkt = K >> 6;
    for (int kt = 0; kt < nkt; ++kt) {
        const int k0 = kt << 6;
        __syncthreads();
        #pragma unroll
        for (int it = 0; it < 4; ++it) {
            int c = tid + it * 256;
            int row = c >> 3, colc = c & 7;
            *reinterpret_cast<uint4*>(&shA[row][colc * 8]) =
                *reinterpret_cast<const uint4*>(&A[(size_t)(bm0 + row) * K + k0 + colc * 8]);
            *reinterpret_cast<uint4*>(&shB[row][colc * 8]) =
                *reinterpret_cast<const uint4*>(&B[(size_t)(bn0 + row) * K + k0 + colc * 8]);
        }
        __syncthreads();
        #pragma unroll
        for (int ks = 0; ks < 2; ++ks) {
            bf16x8 af[4], bfr[4];
            #pragma unroll
            for (int mf = 0; mf < 4; ++mf)
                af[mf] = *reinterpret_cast<const bf16x8*>(&shA[wr * 64 + mf * 16 + l15][ks * 32 + l4 * 8]);
            #pragma unroll
            for (int nf = 0; nf < 4; ++nf)
                bfr[nf] = *reinterpret_cast<const bf16x8*>(&shB[wc * 64 + nf * 16 + l15][ks * 32 + l4 * 8]);
            #pragma unroll
            for (int mf = 0; mf < 4; ++mf)
                #pragma unroll
                for (int nf = 0; nf < 4; ++nf)
                    acc[mf][nf] = __builtin_amdgcn_mfma_f32_16x16x32_bf16(
                        af[mf], bfr[nf], acc[mf][nf], 0, 0, 0);
        }
    }

    #pragma unroll
    for (int mf = 0; mf < 4; ++mf) {
        #pragma unroll
        for (int nf = 0; nf < 4; ++nf) {
            int col = bn0 + wc * 64 + nf * 16 + l15;
            float badd = bias ? bias[col] : 0.f;
            #pragma unroll
            for (int r = 0; r < 4; ++r) {
                int row = bm0 + wr * 64 + mf * 16 + l4 * 4 + r;
                C[(size_t)row * N + col] = acc[mf][nf][r] + badd;
            }
        }
    }
}

// Cross-head L2 norm; Q additionally scaled by log2e/scale[h] (folds softmax
// temperature and the exp->exp2 conversion into the QK^T output).
__global__ __launch_bounds__(256) void normalize_kernel(
    const float* __restrict__ qkv,
    const float* __restrict__ scale,
    unsigned short* __restrict__ qo,
    unsigned short* __restrict__ ko,
    unsigned short* __restrict__ vt)
{
    int t = blockIdx.x * 256 + threadIdx.x;
    int row = t >> 6;
    int d = t & 63;
    int b = row >> 12;
    int n = row & 4095;
    const float* base = qkv + (size_t)row * NQKV;

    float qv[12], kv[12], vv[12];
    float sq = 0.f, sk = 0.f;
    #pragma unroll
    for (int h = 0; h < 12; ++h) {
        qv[h] = base[h * 64 + d];
        kv[h] = base[768 + h * 64 + d];
        vv[h] = base[1536 + h * 64 + d];
        sq += qv[h] * qv[h];
        sk += kv[h] * kv[h];
    }
    float rq = rsqrtf(sqrtf(sq) + EPSF);
    float rk = rsqrtf(sqrtf(sk) + EPSF);
    #pragma unroll
    for (int h = 0; h < 12; ++h) {
        size_t bh = (size_t)(b * 12 + h);
        float fold = LOG2E / scale[h];
        qo[(bh * SEQ + n) * 64 + d] = f2bf(qv[h] * rq * fold);
        ko[(bh * SEQ + n) * 64 + d] = f2bf(kv[h] * rk);
        vt[(bh * 64 + d) * SEQ + n] = f2bf(vv[h]);
    }
}

// Flash attention, 32x32 MFMA, in-register softmax + P, defer-max.
// Grid: (SEQ/128, BATCH*HEADS), 4 waves, each wave owns 32 q-rows.
// S^T[kv][q] = mfma(Kfrag, Qfrag): q = lane&31 lane-local.
//   S^T reg r of half cb holds kv = cb*32 + (r&3) + 8*(r>>2) + 4*hi.
// P -> PV B-frag: cross-hi half-exchange via __shfl_xor(32) + per-lane select.
// O^T[d][q] = mfma(V^T frag, P^T frag): q = lane&31 again lane-local.
__global__ __launch_bounds__(256) void attn_kernel(
    const unsigned short* __restrict__ qg,
    const unsigned short* __restrict__ kg,
    const unsigned short* __restrict__ vtg,
    unsigned short* __restrict__ attnout)
{
    __shared__ unsigned short shK[64][72];   // [kv][d]
    __shared__ unsigned short shV[64][72];   // [d][kv]  (V^T)

    const int qblk = blockIdx.x;
    const int bh   = blockIdx.y;
    const int b    = bh / HEADS;
    const int h    = bh % HEADS;
    const int tid  = threadIdx.x;
    const int lane = tid & 63;
    const int wid  = tid >> 6;
    const int l31  = lane & 31;
    const int hi   = lane >> 5;

    // Q fragments (B operand, col=q=l31, k = d0*16 + hi*8 + j)
    bf16x8 qf[4];
    {
        const unsigned short* qrow =
            qg + ((size_t)bh * SEQ + qblk * 128 + wid * 32 + l31) * 64 + hi * 8;
        #pragma unroll
        for (int d0 = 0; d0 < 4; ++d0)
            qf[d0] = *reinterpret_cast<const bf16x8*>(qrow + d0 * 16);
    }

    f32x16 ot[2];
    #pragma unroll
    for (int r = 0; r < 16; ++r) { ot[0][r] = 0.f; ot[1][r] = 0.f; }
    float m_st = -1e30f, l_st = 0.f;

    const unsigned short* kbase = kg  + (size_t)bh * SEQ * 64;
    const unsigned short* vbase = vtg + (size_t)bh * 64 * SEQ;

    for (int kt = 0; kt < SEQ / 64; ++kt) {
        __syncthreads();
        #pragma unroll
        for (int it = 0; it < 2; ++it) {
            int c = tid + it * 256;
            int row = c >> 3, colc = c & 7;
            *reinterpret_cast<uint4*>(&shK[row][colc * 8]) =
                *reinterpret_cast<const uint4*>(&kbase[(size_t)(kt * 64 + row) * 64 + colc * 8]);
            *reinterpret_cast<uint4*>(&shV[row][colc * 8]) =
                *reinterpret_cast<const uint4*>(&vbase[(size_t)row * SEQ + kt * 64 + colc * 8]);
        }
        __syncthreads();

        // ---- S^T = K * Q^T (already in exp2 domain: scale folded into Q) ----
        f32x16 st0, st1;
        #pragma unroll
        for (int r = 0; r < 16; ++r) { st0[r] = 0.f; st1[r] = 0.f; }
        #pragma unroll
        for (int d0 = 0; d0 < 4; ++d0) {
            bf16x8 kf0 = *reinterpret_cast<const bf16x8*>(&shK[l31][d0 * 16 + hi * 8]);
            bf16x8 kf1 = *reinterpret_cast<const bf16x8*>(&shK[32 + l31][d0 * 16 + hi * 8]);
            st0 = __builtin_amdgcn_mfma_f32_32x32x16_bf16(kf0, qf[d0], st0, 0, 0, 0);
            st1 = __builtin_amdgcn_mfma_f32_32x32x16_bf16(kf1, qf[d0], st1, 0, 0, 0);
        }

        // ---- column max (lane-local 32 values + cross-half exchange) ----
        float mx = st0[0];
        #pragma unroll
        for (int r = 1; r < 16; ++r) mx = fmaxf(mx, st0[r]);
        #pragma unroll
        for (int r = 0; r < 16; ++r) mx = fmaxf(mx, st1[r]);
        mx = fmaxf(mx, __shfl_xor(mx, 32));

        // ---- defer-max: rescale only when max grew by > 8 (2^8 bound on P) ----
        if (!__all(mx <= m_st + 8.0f)) {
            float m_new = fmaxf(m_st, mx);
            float alpha = __builtin_amdgcn_exp2f(m_st - m_new);
            l_st *= alpha;
            #pragma unroll
            for (int r = 0; r < 16; ++r) { ot[0][r] *= alpha; ot[1][r] *= alpha; }
            m_st = m_new;
        }

        // ---- P = exp2(S - m), packed to bf16 pairs in-register ----
        float sum = 0.f;
        unsigned cp0[8], cp1[8];
        #pragma unroll
        for (int t = 0; t < 8; ++t) {
            float pa = __builtin_amdgcn_exp2f(st0[2 * t]     - m_st);
            float pb = __builtin_amdgcn_exp2f(st0[2 * t + 1] - m_st);
            float pc = __builtin_amdgcn_exp2f(st1[2 * t]     - m_st);
            float pd = __builtin_amdgcn_exp2f(st1[2 * t + 1] - m_st);
            sum += (pa + pb) + (pc + pd);
            cp0[t] = pkbf(pa, pb);
            cp1[t] = pkbf(pc, pd);
        }
        sum += __shfl_xor(sum, 32);
        l_st += sum;

        // ---- O^T += V^T * P^T ----
        // B-frag for k-slice (cb,kk): lane needs kv = cb*32+kk*16+8*hi+{2j,2j+1}.
        // Own regs hold kv offsets {4hi+0..3, 8+4hi+0..3, ...}; the missing half
        // lives on the lane^32 partner -> shfl_xor + select.
        #pragma unroll
        for (int cb = 0; cb < 2; ++cb) {
            #pragma unroll
            for (int kk = 0; kk < 2; ++kk) {
                unsigned c0 = cb ? cp1[4 * kk + 0] : cp0[4 * kk + 0];
                unsigned c1 = cb ? cp1[4 * kk + 1] : cp0[4 * kk + 1];
                unsigned c2 = cb ? cp1[4 * kk + 2] : cp0[4 * kk + 2];
                unsigned c3 = cb ? cp1[4 * kk + 3] : cp0[4 * kk + 3];
                unsigned e0 = __shfl_xor(c0, 32);
                unsigned e1 = __shfl_xor(c1, 32);
                unsigned e2 = __shfl_xor(c2, 32);
                unsigned e3 = __shfl_xor(c3, 32);
                union { unsigned u[4]; bf16x8 v; } pu;
                pu.u[0] = hi ? e2 : c0;   // k = 8hi+0,1
                pu.u[1] = hi ? e3 : c1;   // k = 8hi+2,3
                pu.u[2] = hi ? c2 : e0;   // k = 8hi+4,5
                pu.u[3] = hi ? c3 : e1;   // k = 8hi+6,7
                #pragma unroll
                for (int df = 0; df < 2; ++df) {
                    bf16x8 vf = *reinterpret_cast<const bf16x8*>(
                        &shV[df * 32 + l31][cb * 32 + kk * 16 + hi * 8]);
                    ot[df] = __builtin_amdgcn_mfma_f32_32x32x16_bf16(vf, pu.v, ot[df], 0, 0, 0);
                }
            }
        }
    }

    // ---- epilogue: O[q][d] = O^T[d][q] / l, q = l31 lane-local ----
    float invl = 1.0f / l_st;
    int n = qblk * 128 + wid * 32 + l31;
    unsigned short* orow = attnout + ((size_t)(b * SEQ + n)) * INNER + h * 64;
    #pragma unroll
    for (int df = 0; df < 2; ++df) {
        #pragma unroll
        for (int t = 0; t < 4; ++t) {
            // regs 4t..4t+3 -> d = df*32 + t*8 + hi*4 + (0..3), contiguous quad
            unsigned w0 = pkbf(ot[df][4 * t]     * invl, ot[df][4 * t + 1] * invl);
            unsigned w1 = pkbf(ot[df][4 * t + 2] * invl, ot[df][4 * t + 3] * invl);
            unsigned long long pk = (unsigned long long)w0 | ((unsigned long long)w1 << 32);
            *reinterpret_cast<unsigned long long*>(orow + df * 32 + t * 8 + hi * 4) = pk;
        }
    }
}

extern "C" void kernel_launch(void* const* d_in, const int* in_sizes, int n_in,
                              void* d_out, int out_size, void* d_ws, size_t ws_size,
                              hipStream_t stream)
{
    const float* x      = (const float*)d_in[0];
    const float* w_qkv  = (const float*)d_in[1];
    const float* w_out  = (const float*)d_in[2];
    const float* b_out  = (const float*)d_in[3];
    const float* scale  = (const float*)d_in[4];
    float* out = (float*)d_out;
    char* ws = (char*)d_ws;

    unsigned short* xb    = (unsigned short*)(ws);                 // 12,582,912
    unsigned short* wqkvb = (unsigned short*)(ws + 12582912);      //  3,538,944
    unsigned short* woutb = (unsigned short*)(ws + 16121856);      //  1,179,648
    unsigned short* attnb = (unsigned short*)(ws + 17301504);      // 12,582,912
    unsigned short* qb    = (unsigned short*)(ws + 29884416);      // 12,582,912
    unsigned short* kb    = (unsigned short*)(ws + 42467328);      // 12,582,912
    unsigned short* vtb   = (unsigned short*)(ws + 55050240);      // 12,582,912
    float*          qkvf  = (float*)(ws + 67633152);               // 75,497,472

    cast_f32_bf16<<<6144, 256, 0, stream>>>(x, xb, 6291456);
    cast_f32_bf16<<<1728, 256, 0, stream>>>(w_qkv, wqkvb, 1769472);
    cast_f32_bf16<<<576, 256, 0, stream>>>(w_out, woutb, 589824);

    gemm_bt_kernel<<<dim3(64, 18), 256, 0, stream>>>(xb, wqkvb, qkvf, nullptr, ROWS, NQKV, DIMX);

    normalize_kernel<<<2048, 256, 0, stream>>>(qkvf, scale, qb, kb, vtb);

    attn_kernel<<<dim3(SEQ / 128, BATCH * HEADS), 256, 0, stream>>>(qb, kb, vtb, attnb);

    gemm_bt_kernel<<<dim3(64, 6), 256, 0, stream>>>(attnb, woutb, out, b_out, ROWS, INNER, INNER);
}